// Round 11
// baseline (98.398 us; speedup 1.0000x reference)
//
#include <hip/hip_runtime.h>
#include <hip/hip_bf16.h>
#include <math.h>

// Problem constants
#define NB 8
#define LN 4096       // sequence length L
#define NH 8
#define NE 64
#define NC 512        // NH*NE channels
#define NM 64         // modes kept
#define LMASK 4095

typedef short s16x8 __attribute__((ext_vector_type(8)));
typedef float f32x4 __attribute__((ext_vector_type(4)));
typedef const __attribute__((address_space(1))) void gv_t;
typedef __attribute__((address_space(3))) void lv_t;

// ws layout (in floats):
//  egf : bf16[128kc][8mt][64][8]        @ 0        (1 MB)  fwd twiddle A-fragments
//  tf  : bf16[4kk][256lt][64][8]        @ 262144   (1 MB)  inv twiddle B-fragments
//  gf  : bf16[8b][4kk][32ct][64][8]     @ 524288   (1 MB)  mixed-spectrum A-fragments
//  xp  : f32[8ks][8b][8h][64i][128m±]   @ 786432   (16 MB) partial fwd GEMM outputs
//  xs  : f32[8b][8h][64i][128m±]        @ 4980736  (2 MB)  ks-summed spectrum
#define WS_EGF 0
#define WS_TF  262144
#define WS_GF  524288
#define WS_XP  786432
#define WS_XS  4980736

static __device__ __forceinline__ unsigned short bf16bits(float f) {
    __hip_bfloat16 b = __float2bfloat16(f);
    return *reinterpret_cast<unsigned short*>(&b);
}

// Both twiddle tables in one launch. Blocks 0..255: egf (fwd A-frags);
// blocks 256..511: tf (inv B-frags).
__global__ __launch_bounds__(256) void k_tables(unsigned short* __restrict__ egf,
                                                unsigned short* __restrict__ tfp) {
    const int bid = blockIdx.x;
    const int s = (bid & 255) * 256 + threadIdx.x;   // 0..65535
    const int lane = s & 63;
    unsigned short v[8];
    if (bid < 256) {
        // E[2m][l]=cos, E[2m+1][l]=-sin ; slot s=(kc<<9)|(mt<<6)|lane
        int mt = (s >> 6) & 7, kc = s >> 9;
        int r = lane & 15, kg = lane >> 4;
        int mpm = mt * 16 + r;
        int m = mpm >> 1, isim = mpm & 1;
        #pragma unroll
        for (int j = 0; j < 8; ++j) {
            int l = kc * 32 + kg * 8 + j;
            int tw = (m * l) & LMASK;
            float ang = (6.283185307179586f / 4096.0f) * (float)tw;
            v[j] = bf16bits(isim ? -sinf(ang) : cosf(ang));
        }
    } else {
        // T[l][2m]=cos, T[l][2m+1]=sin ; slot s=(kk<<14)|(lt<<6)|lane
        int lt = (s >> 6) & 255, kk = s >> 14;
        int l = lt * 16 + (lane & 15);
        int khi = (lane >> 4) * 8;
        #pragma unroll
        for (int j = 0; j < 8; ++j) {
            int mp = kk * 32 + khi + j;
            int m = mp >> 1;
            int tw = (m * l) & LMASK;
            float ang = (6.283185307179586f / 4096.0f) * (float)tw;
            v[j] = bf16bits((mp & 1) ? sinf(ang) : cosf(ang));
        }
    }
    uint4 pk;
    pk.x = (unsigned)v[0] | ((unsigned)v[1] << 16);
    pk.y = (unsigned)v[2] | ((unsigned)v[3] << 16);
    pk.z = (unsigned)v[4] | ((unsigned)v[5] << 16);
    pk.w = (unsigned)v[6] | ((unsigned)v[7] << 16);
    unsigned short* dst = (bid < 256) ? egf : tfp;
    *reinterpret_cast<uint4*>(dst + (size_t)s * 8) = pk;
}

// ---------------------------------------------------------------------------
// Fused stage 1 (v7 = v6 pipeline + CONTIGUOUS staging + bank-free gather).
// grid (8 ks, 8 h, 8 b), 256 thr = 4 waves, 2 blocks/CU.
// qlds [4 slot][32 l][64 i] f32 (32 KB): each global_load_lds now covers 4 FULL
// 256B q-rows (lane -> row lane>>4, chunk lane&15), vs v6's 16x64B scatter.
// Chunk XOR-pre-swizzle by w on the source; bfr read XORs by g -> conflict-free.
// eglds [4][4096] bf16 (32 KB) unchanged. vmcnt(8) math unchanged (2Q+2E/tile/wave).
// kc order + RNE cvt identical -> absmax must stay exactly 2.384186e-07.
// ---------------------------------------------------------------------------
__global__ __launch_bounds__(256, 2) void k_fs1(const float* __restrict__ q,
                                                const unsigned short* __restrict__ egf,
                                                float* __restrict__ xp) {
    __shared__ float qlds[4][32][64];
    __shared__ unsigned short eglds[4][4096];
    const int ks = blockIdx.x, h = blockIdx.y, b = blockIdx.z;
    const int tid = threadIdx.x;
    const int w = tid >> 6, lane = tid & 63;
    const int g = lane >> 4, r = lane & 15;

    // staging source: lane covers (row = g of 4, 16B chunk = r ^ w) of a 32lx64i tile
    const float* qsrc = q + (((size_t)b * LN + ks * 512 + g) * NH + h) * NE + ((r ^ w) << 2);
    // egf tile t = one kc = 4096 shorts; wave w stages quarter w
    const unsigned short* esrc = egf + (size_t)(ks * 16) * 4096 + w * 1024 + lane * 8;

#define STAGE_Q(T) { \
    __builtin_amdgcn_global_load_lds((gv_t*)(qsrc + (size_t)((T) * 32 + w * 8) * NC), \
        (lv_t*)(&qlds[(T) & 3][w * 8][0]), 16, 0, 0); \
    __builtin_amdgcn_global_load_lds((gv_t*)(qsrc + (size_t)((T) * 32 + w * 8 + 4) * NC), \
        (lv_t*)(&qlds[(T) & 3][w * 8 + 4][0]), 16, 0, 0); }

#define STAGE_E(T) { \
    __builtin_amdgcn_global_load_lds((gv_t*)(esrc + (size_t)(T) * 4096), \
        (lv_t*)(&eglds[(T) & 3][w * 1024]), 16, 0, 0); \
    __builtin_amdgcn_global_load_lds((gv_t*)(esrc + (size_t)(T) * 4096 + 512), \
        (lv_t*)(&eglds[(T) & 3][w * 1024 + 512]), 16, 0, 0); }

    f32x4 acc[8];
    #pragma unroll
    for (int mt = 0; mt < 8; ++mt) acc[mt] = (f32x4)(0.0f);

    // Prologue (issue order matters for in-order vmcnt math): q0,e0,e1,q1,q2
    STAGE_Q(0) STAGE_E(0) STAGE_E(1) STAGE_Q(1) STAGE_Q(2)

    // bfr gather base: logical (l = g*8+j, i = w*16+r); phys chunk = (i>>2) ^ g
    const int rb = (((w * 4 + (r >> 2)) ^ g) << 2) + (r & 3);

    #pragma unroll
    for (int t = 0; t < 16; ++t) {
        if (t + 2 < 16) STAGE_E(t + 2)
        // Force q(t) & egf(t) resident; keep {q(t+1),q(t+2),e(t+1),e(t+2)} in flight.
        if (t <= 13)      asm volatile("s_waitcnt vmcnt(8)" ::: "memory");
        else if (t == 14) asm volatile("s_waitcnt vmcnt(4)" ::: "memory");
        else              asm volatile("s_waitcnt vmcnt(0)" ::: "memory");
        __builtin_amdgcn_s_barrier();          // raw barrier: no vmcnt drain
        asm volatile("" ::: "memory");
        if (t + 3 < 16) STAGE_Q(t + 3)

        // A fragments from LDS (lane-contiguous b128 reads)
        s16x8 af[8];
        #pragma unroll
        for (int mt = 0; mt < 8; ++mt)
            af[mt] = *reinterpret_cast<const s16x8*>(&eglds[t & 3][mt * 512 + lane * 8]);
        // B fragment: swizzled f32 gather, cvt to bf16 (same RNE as before)
        const float* qs = &qlds[t & 3][0][0];
        s16x8 bfr;
        #pragma unroll
        for (int j = 0; j < 8; ++j)
            bfr[j] = (short)bf16bits(qs[(g * 8 + j) * 64 + rb]);

        #pragma unroll
        for (int mt = 0; mt < 8; ++mt)
            acc[mt] = __builtin_amdgcn_mfma_f32_16x16x32_bf16(af[mt], bfr, acc[mt], 0, 0, 0);
    }

    // Epilogue: D row = m±-local = (lane>>4)*4 + reg, col = i-local = lane&15.
    const int i = w * 16 + r;
    float* xpb = xp + ((size_t)ks * 64 + b * 8 + h) * (64 * 128) + (size_t)i * 128 + g * 4;
    #pragma unroll
    for (int mt = 0; mt < 8; ++mt)
        *reinterpret_cast<f32x4*>(xpb + mt * 16) = acc[mt];
#undef STAGE_Q
#undef STAGE_E
}

// ---------------------------------------------------------------------------
// PROBE (diagnostic, output-free): v7 staging loop only, x4 repeats.
// Measures whether the global_load_lds pattern can stream q at HBM/L3 BW.
// Kept alive via asm; writes nothing. Expected 44-140 us -> visible in top-5.
// ---------------------------------------------------------------------------
__global__ __launch_bounds__(256, 2) void k_pstage(const float* __restrict__ q,
                                                   const unsigned short* __restrict__ egf) {
    __shared__ float qlds[4][32][64];
    __shared__ unsigned short eglds[4][4096];
    const int ks = blockIdx.x, h = blockIdx.y, b = blockIdx.z;
    const int tid = threadIdx.x;
    const int w = tid >> 6, lane = tid & 63;
    const int g = lane >> 4, r = lane & 15;

    const float* qsrc = q + (((size_t)b * LN + ks * 512 + g) * NH + h) * NE + ((r ^ w) << 2);
    const unsigned short* esrc = egf + (size_t)(ks * 16) * 4096 + w * 1024 + lane * 8;

#define STAGE_Q(T) { \
    __builtin_amdgcn_global_load_lds((gv_t*)(qsrc + (size_t)((T) * 32 + w * 8) * NC), \
        (lv_t*)(&qlds[(T) & 3][w * 8][0]), 16, 0, 0); \
    __builtin_amdgcn_global_load_lds((gv_t*)(qsrc + (size_t)((T) * 32 + w * 8 + 4) * NC), \
        (lv_t*)(&qlds[(T) & 3][w * 8 + 4][0]), 16, 0, 0); }

#define STAGE_E(T) { \
    __builtin_amdgcn_global_load_lds((gv_t*)(esrc + (size_t)(T) * 4096), \
        (lv_t*)(&eglds[(T) & 3][w * 1024]), 16, 0, 0); \
    __builtin_amdgcn_global_load_lds((gv_t*)(esrc + (size_t)(T) * 4096 + 512), \
        (lv_t*)(&eglds[(T) & 3][w * 1024 + 512]), 16, 0, 0); }

    for (int rep = 0; rep < 4; ++rep) {
        STAGE_Q(0) STAGE_E(0) STAGE_E(1) STAGE_Q(1) STAGE_Q(2)
        for (int t = 0; t < 16; ++t) {
            if (t + 2 < 16) STAGE_E(t + 2)
            if (t <= 13)      asm volatile("s_waitcnt vmcnt(8)" ::: "memory");
            else if (t == 14) asm volatile("s_waitcnt vmcnt(4)" ::: "memory");
            else              asm volatile("s_waitcnt vmcnt(0)" ::: "memory");
            __builtin_amdgcn_s_barrier();
            asm volatile("" ::: "memory");
            if (t + 3 < 16) STAGE_Q(t + 3)
        }
        asm volatile("s_waitcnt vmcnt(0)" ::: "memory");
        __builtin_amdgcn_s_barrier();
    }
    float v = qlds[0][tid & 31][lane] + (float)eglds[0][tid * 4];
    asm volatile("" :: "v"(v));   // keep staging live (rule #17), no output
#undef STAGE_Q
#undef STAGE_E
}

// Sum the 8 K-split partials (float4-vectorized; same per-element order).
__global__ __launch_bounds__(256) void k_presum(const float* __restrict__ xp,
                                                float* __restrict__ xs) {
    int e4 = blockIdx.x * 256 + threadIdx.x;     // 0..131071 float4s
    const f32x4* xp4 = reinterpret_cast<const f32x4*>(xp);
    f32x4 s = (f32x4)(0.0f);
    #pragma unroll
    for (int ks = 0; ks < 8; ++ks) s += xp4[(size_t)ks * 131072 + e4];
    reinterpret_cast<f32x4*>(xs)[e4] = s;
}

// Stage 2 (v3, proven): channel mix, gf written directly. grid 256 blocks
// (XCD-swizzled), block 256. Block stages xs[2b][h][64i][64m] (64 KB) to LDS,
// then the o-loop runs from LDS; w1/w2 read exactly once across the grid.
__global__ __launch_bounds__(256) void k_s2(const float* __restrict__ w1,
                                            const float* __restrict__ w2,
                                            const float* __restrict__ xs,
                                            unsigned short* __restrict__ gf) {
    __shared__ float2 sxs[2][64][64];    // [bsub][i][m] = 64 KB
    const int sid = blockIdx.x;
    const int x   = sid & 7;
    const int idx = sid >> 3;
    const int r   = x * 8 + (idx & 7);   // (og,h) index
    const int og  = r >> 3, h = r & 7;
    const int bb  = idx >> 3;            // 0..3
    const int tt  = threadIdx.x;

    {
        float4* dst = reinterpret_cast<float4*>(&sxs[0][0][0]);
        #pragma unroll
        for (int bs = 0; bs < 2; ++bs) {
            const float4* s4 = reinterpret_cast<const float4*>(
                xs + ((size_t)((bb * 2 + bs) * 8 + h)) * 8192);
            #pragma unroll
            for (int k = 0; k < 8; ++k)
                dst[bs * 2048 + k * 256 + tt] = s4[k * 256 + tt];
        }
    }
    __syncthreads();

    const int m    = tt & 63;
    const int osub = tt >> 6;            // 0..3
    const int o0   = og * 8 + osub * 2;  // 2 o per thread

    float re[2][2], im[2][2];            // [oo][bs]
    #pragma unroll
    for (int oo = 0; oo < 2; ++oo)
        #pragma unroll
        for (int bs = 0; bs < 2; ++bs) { re[oo][bs] = 0.f; im[oo][bs] = 0.f; }

    const float* w1p = w1 + (size_t)h * (NE * NE * NM) + (size_t)o0 * NM + m;
    const float* w2p = w2 + (size_t)h * (NE * NE * NM) + (size_t)o0 * NM + m;

    #pragma unroll 2
    for (int i = 0; i < NE; ++i) {
        float wr0 = w1p[(size_t)i * (NE * NM)];
        float wi0 = w2p[(size_t)i * (NE * NM)];
        float wr1 = w1p[(size_t)i * (NE * NM) + NM];
        float wi1 = w2p[(size_t)i * (NE * NM) + NM];
        #pragma unroll
        for (int bs = 0; bs < 2; ++bs) {
            float2 xv = sxs[bs][i][m];
            re[0][bs] = fmaf(xv.x, wr0, fmaf(-xv.y, wi0, re[0][bs]));
            im[0][bs] = fmaf(xv.x, wi0, fmaf( xv.y, wr0, im[0][bs]));
            re[1][bs] = fmaf(xv.x, wr1, fmaf(-xv.y, wi1, re[1][bs]));
            im[1][bs] = fmaf(xv.x, wi1, fmaf( xv.y, wr1, im[1][bs]));
        }
    }

    const float sca = (m == 0 ? 1.0f : 2.0f) / (float)LN;  // (2-delta_m0)/L fold
    const int kk  = m >> 4;
    const int khi = ((m & 15) >> 2) * 16;
    const int jj  = (m & 3) << 1;
    #pragma unroll
    for (int oo = 0; oo < 2; ++oo) {
        const int c = h * 64 + o0 + oo;
        #pragma unroll
        for (int bs = 0; bs < 2; ++bs) {
            const int b = bb * 2 + bs;
            size_t slot = (((size_t)b * 4 + kk) * 32 + (c >> 4)) * 64 + khi + (c & 15);
            unsigned int pk = (unsigned)bf16bits(re[oo][bs] * sca) |
                              ((unsigned)bf16bits(-im[oo][bs] * sca) << 16);
            *reinterpret_cast<unsigned int*>(gf + slot * 8 + jj) = pk;
        }
    }
}

// Stage 3 MFMA: per b: out[l][c] = sum_mp T[l][mp] * G[mp][c].  M=c(128/block), N=l(64/block), K=128.
// grid (64 lb, 4 cb, 8 b), block 256 = 4 waves; wave w owns c-quarter [w*32, w*32+32).
// Zero LDS / zero barriers; both operand tables stream from L2.
__global__ __launch_bounds__(256, 2) void k_s3(const unsigned short* __restrict__ gf,
                                               const unsigned short* __restrict__ tfp,
                                               float* __restrict__ out) {
    const int lb = blockIdx.x;   // l base = lb*64
    const int cb = blockIdx.y;   // c base = cb*128
    const int b  = blockIdx.z;
    const int tid = threadIdx.x;
    const int w = tid >> 6, lane = tid & 63;

    const unsigned short* ga = gf + ((((size_t)b * 4) * 32 + cb * 8 + w * 2) * 64 + lane) * 8;
    const unsigned short* tb = tfp + (((size_t)lb * 4) * 64 + lane) * 8;

    f32x4 acc[2][4] = {};
    s16x8 af[3][2], bf[3][4];

#define S3_LOAD(T, SLOT)                                                          \
    {                                                                             \
        const unsigned short* gp_ = ga + (size_t)(T) * (32 * 64 * 8);             \
        const unsigned short* tp_ = tb + (size_t)(T) * (256 * 64 * 8);            \
        af[SLOT][0] = *reinterpret_cast<const s16x8*>(gp_);                       \
        af[SLOT][1] = *reinterpret_cast<const s16x8*>(gp_ + 64 * 8);              \
        bf[SLOT][0] = *reinterpret_cast<const s16x8*>(tp_);                       \
        bf[SLOT][1] = *reinterpret_cast<const s16x8*>(tp_ + 64 * 8);              \
        bf[SLOT][2] = *reinterpret_cast<const s16x8*>(tp_ + 2 * 64 * 8);          \
        bf[SLOT][3] = *reinterpret_cast<const s16x8*>(tp_ + 3 * 64 * 8);          \
    }

    S3_LOAD(0, 0)
    S3_LOAD(1, 1)

    #pragma unroll
    for (int t = 0; t < 4; ++t) {
        const int slot = t % 3;
        if (t + 2 < 4) { const int ns = (t + 2) % 3; S3_LOAD(t + 2, ns) }
        #pragma unroll
        for (int mi = 0; mi < 2; ++mi)
            #pragma unroll
            for (int ni = 0; ni < 4; ++ni)
                acc[mi][ni] = __builtin_amdgcn_mfma_f32_16x16x32_bf16(
                    af[slot][mi], bf[slot][ni], acc[mi][ni], 0, 0, 0);
    }
#undef S3_LOAD

    // D[row=c_local][col=l_local]; f32x4 regs span 4 consecutive c.
    const int c0 = cb * 128 + w * 32 + (lane >> 4) * 4;
    const int l0 = lb * 64 + (lane & 15);
    #pragma unroll
    for (int mi = 0; mi < 2; ++mi)
        #pragma unroll
        for (int ni = 0; ni < 4; ++ni) {
            float* op = out + ((size_t)b * LN + l0 + ni * 16) * NC + c0 + mi * 16;
            *reinterpret_cast<f32x4*>(op) = acc[mi][ni];
        }
}

extern "C" void kernel_launch(void* const* d_in, const int* in_sizes, int n_in,
                              void* d_out, int out_size, void* d_ws, size_t ws_size,
                              hipStream_t stream) {
    const float* q  = (const float*)d_in[0];
    // d_in[1] (k) and d_in[2] (v) are unused by the reference
    const float* w1 = (const float*)d_in[3];
    const float* w2 = (const float*)d_in[4];
    float* out = (float*)d_out;
    float* ws  = (float*)d_ws;

    unsigned short* egf = (unsigned short*)(ws + WS_EGF);
    unsigned short* tfp = (unsigned short*)(ws + WS_TF);
    unsigned short* gf  = (unsigned short*)(ws + WS_GF);
    float*          xp  = ws + WS_XP;
    float*          xs  = ws + WS_XS;

    k_tables<<<512, 256, 0, stream>>>(egf, tfp);
    k_fs1<<<dim3(8, NH, NB), 256, 0, stream>>>(q, egf, xp);
    k_presum<<<512, 256, 0, stream>>>(xp, xs);
    k_s2<<<256, 256, 0, stream>>>(w1, w2, xs, gf);
    k_s3<<<dim3(64, 4, NB), 256, 0, stream>>>(gf, tfp, out);
    // diagnostic probe (no outputs): staging-only x4, visible in rocprof top-5
    k_pstage<<<dim3(8, NH, NB), 256, 0, stream>>>(q, egf);
}

// Round 12
// 70.389 us; speedup vs baseline: 1.3979x; 1.3979x over previous
//
#include <hip/hip_runtime.h>
#include <hip/hip_bf16.h>
#include <math.h>

// Problem constants
#define NB 8
#define LN 4096       // sequence length L
#define NH 8
#define NE 64
#define NC 512        // NH*NE channels
#define NM 64         // modes kept
#define LMASK 4095

typedef short s16x8 __attribute__((ext_vector_type(8)));
typedef float f32x4 __attribute__((ext_vector_type(4)));

// ws layout (in floats):
//  egf : bf16[128kc][8mt][64][8]          @ 0         (1 MB)  fwd twiddle A-fragments
//  tf  : bf16[4kk][256lt][64][8]          @ 262144    (1 MB)  inv twiddle B-fragments
//  gf  : bf16[8b][4kk][32ct][64][8]       @ 524288    (1 MB)  mixed-spectrum A-fragments
//  qtf : bf16[8b][8h][128kc][4nt][64][8]  @ 786432    (32 MB) q B-fragments
//  xp  : f32[8ks][8b][8h][64i][128m±]     @ 9175040   (16 MB) partial fwd GEMM outputs
//  xs  : f32[8b][8h][64i][128m±]          @ 13369344  (2 MB)  ks-summed spectrum
#define WS_EGF 0
#define WS_TF  262144
#define WS_GF  524288
#define WS_QTF 786432
#define WS_XP  9175040
#define WS_XS  13369344

static __device__ __forceinline__ unsigned short bf16bits(float f) {
    __hip_bfloat16 b = __float2bfloat16(f);
    return *reinterpret_cast<unsigned short*>(&b);
}

// Merged prep kernel: blocks 0..8191 build qtf (q -> bf16 B-fragments);
// blocks 8192..8447 build egf; blocks 8448..8703 build tf. One launch.
__global__ __launch_bounds__(256) void k_pre(const float* __restrict__ q,
                                             unsigned short* __restrict__ qtf,
                                             unsigned short* __restrict__ egf,
                                             unsigned short* __restrict__ tfp) {
    const int bid = blockIdx.x;
    unsigned short v[8];
    if (bid < 8192) {
        // qtf: slot s = b<<18 | h<<15 | kc<<8 | nt<<6 | lane.
        // Elem j: q[b][ l = kc*32 + (lane>>4)*8 + j ][h][ i = nt*16 + (lane&15) ]
        const int s = bid * 256 + threadIdx.x;       // 0..2097151
        const int lane = s & 63, nt = (s >> 6) & 3, kc = (s >> 8) & 127,
                  h = (s >> 15) & 7, b = s >> 18;
        const int i = nt * 16 + (lane & 15);
        const int l0 = kc * 32 + (lane >> 4) * 8;
        const float* qp = q + (((size_t)b * LN + l0) * NH + h) * NE + i;
        #pragma unroll
        for (int j = 0; j < 8; ++j) v[j] = bf16bits(qp[(size_t)j * NC]);
        uint4 pk;
        pk.x = (unsigned)v[0] | ((unsigned)v[1] << 16);
        pk.y = (unsigned)v[2] | ((unsigned)v[3] << 16);
        pk.z = (unsigned)v[4] | ((unsigned)v[5] << 16);
        pk.w = (unsigned)v[6] | ((unsigned)v[7] << 16);
        *reinterpret_cast<uint4*>(qtf + (size_t)s * 8) = pk;
        return;
    }
    const int bid2 = bid - 8192;                     // 0..511
    const int s = (bid2 & 255) * 256 + threadIdx.x;  // 0..65535
    const int lane = s & 63;
    if (bid2 < 256) {
        // egf: E[2m][l]=cos, E[2m+1][l]=-sin ; slot s=(kc<<9)|(mt<<6)|lane
        int mt = (s >> 6) & 7, kc = s >> 9;
        int r = lane & 15, kg = lane >> 4;
        int mpm = mt * 16 + r;
        int m = mpm >> 1, isim = mpm & 1;
        #pragma unroll
        for (int j = 0; j < 8; ++j) {
            int l = kc * 32 + kg * 8 + j;
            int tw = (m * l) & LMASK;
            float ang = (6.283185307179586f / 4096.0f) * (float)tw;
            v[j] = bf16bits(isim ? -sinf(ang) : cosf(ang));
        }
    } else {
        // tf: T[l][2m]=cos, T[l][2m+1]=sin ; slot s=(kk<<14)|(lt<<6)|lane
        int lt = (s >> 6) & 255, kk = s >> 14;
        int l = lt * 16 + (lane & 15);
        int khi = (lane >> 4) * 8;
        #pragma unroll
        for (int j = 0; j < 8; ++j) {
            int mp = kk * 32 + khi + j;
            int m = mp >> 1;
            int tw = (m * l) & LMASK;
            float ang = (6.283185307179586f / 4096.0f) * (float)tw;
            v[j] = bf16bits((mp & 1) ? sinf(ang) : cosf(ang));
        }
    }
    uint4 pk;
    pk.x = (unsigned)v[0] | ((unsigned)v[1] << 16);
    pk.y = (unsigned)v[2] | ((unsigned)v[3] << 16);
    pk.z = (unsigned)v[4] | ((unsigned)v[5] << 16);
    pk.w = (unsigned)v[6] | ((unsigned)v[7] << 16);
    unsigned short* dst = (bid2 < 256) ? egf : tfp;
    *reinterpret_cast<uint4*>(dst + (size_t)s * 8) = pk;
}

// Stage 1 MFMA (round-3 proven structure): per (ks,h,b):
// Xp[ks][b][h][i][m±] = E[m±][l] * q[l][i] over the 512-l chunk.
// grid (8 ks, 8 h, 8 b), block 256 = 4 waves; wave w owns m± quarter [w*32,+32).
// Zero LDS, zero barriers: fragments stream from L2/L3 with a 3-slot 2-deep ring.
// (Natural dispatch puts all 64 same-ks blocks on one XCD -> egf slice L2-hits.)
__global__ __launch_bounds__(256, 2) void k_s1(const unsigned short* __restrict__ qtf,
                                               const unsigned short* __restrict__ egf,
                                               float* __restrict__ xp) {
    const int ks = blockIdx.x, h = blockIdx.y, b = blockIdx.z;
    const int tid = threadIdx.x;
    const int w = tid >> 6, lane = tid & 63;
    const int kc0 = ks * 16;

    const unsigned short* qb = qtf + ((((size_t)(b * 8 + h) * 128 + kc0) * 4) * 64 + lane) * 8;
    const unsigned short* eb = egf + (((size_t)kc0 * 8 + w * 2) * 64 + lane) * 8;

    f32x4 acc[2][4] = {};
    s16x8 af[3][2], bf[3][4];

#define S1_LOAD(T, SLOT)                                                          \
    {                                                                             \
        const unsigned short* ep_ = eb + (size_t)(T) * (8 * 64 * 8);              \
        const unsigned short* qp_ = qb + (size_t)(T) * (4 * 64 * 8);              \
        af[SLOT][0] = *reinterpret_cast<const s16x8*>(ep_);                       \
        af[SLOT][1] = *reinterpret_cast<const s16x8*>(ep_ + 64 * 8);              \
        bf[SLOT][0] = *reinterpret_cast<const s16x8*>(qp_);                       \
        bf[SLOT][1] = *reinterpret_cast<const s16x8*>(qp_ + 64 * 8);              \
        bf[SLOT][2] = *reinterpret_cast<const s16x8*>(qp_ + 2 * 64 * 8);          \
        bf[SLOT][3] = *reinterpret_cast<const s16x8*>(qp_ + 3 * 64 * 8);          \
    }

    S1_LOAD(0, 0)
    S1_LOAD(1, 1)

    #pragma unroll
    for (int t = 0; t < 16; ++t) {
        const int slot = t % 3;
        if (t + 2 < 16) { const int ns = (t + 2) % 3; S1_LOAD(t + 2, ns) }
        #pragma unroll
        for (int mi = 0; mi < 2; ++mi)
            #pragma unroll
            for (int ni = 0; ni < 4; ++ni)
                acc[mi][ni] = __builtin_amdgcn_mfma_f32_16x16x32_bf16(
                    af[slot][mi], bf[slot][ni], acc[mi][ni], 0, 0, 0);
    }
#undef S1_LOAD

    // Epilogue: D row = m±-local = (lane>>4)*4 + reg, col = i-local = lane&15.
    const int r4 = (lane >> 4) * 4, c = lane & 15;
    float* xpb = xp + ((size_t)ks * 64 + b * 8 + h) * (64 * 128);   // [i][128 m±]
    #pragma unroll
    for (int mi = 0; mi < 2; ++mi)
        #pragma unroll
        for (int ni = 0; ni < 4; ++ni) {
            int i  = ni * 16 + c;
            int mb = w * 32 + mi * 16 + r4;
            *reinterpret_cast<f32x4*>(xpb + (size_t)i * 128 + mb) = acc[mi][ni];
        }
}

// Sum the 8 K-split partials (float4-vectorized; ks ascending = same order).
__global__ __launch_bounds__(256) void k_presum(const float* __restrict__ xp,
                                                float* __restrict__ xs) {
    int e4 = blockIdx.x * 256 + threadIdx.x;     // 0..131071 float4s
    const f32x4* xp4 = reinterpret_cast<const f32x4*>(xp);
    f32x4 s = (f32x4)(0.0f);
    #pragma unroll
    for (int ks = 0; ks < 8; ++ks) s += xp4[(size_t)ks * 131072 + e4];
    reinterpret_cast<f32x4*>(xs)[e4] = s;
}

// Stage 2 (v3, proven): channel mix, gf written directly. grid 256 blocks
// (XCD-swizzled), block 256. Block stages xs[2b][h][64i][64m] (64 KB) to LDS,
// then the o-loop runs from LDS; w1/w2 read exactly once across the grid.
__global__ __launch_bounds__(256) void k_s2(const float* __restrict__ w1,
                                            const float* __restrict__ w2,
                                            const float* __restrict__ xs,
                                            unsigned short* __restrict__ gf) {
    __shared__ float2 sxs[2][64][64];    // [bsub][i][m] = 64 KB
    const int sid = blockIdx.x;
    const int x   = sid & 7;
    const int idx = sid >> 3;
    const int r   = x * 8 + (idx & 7);   // (og,h) index
    const int og  = r >> 3, h = r & 7;
    const int bb  = idx >> 3;            // 0..3
    const int tt  = threadIdx.x;

    {
        float4* dst = reinterpret_cast<float4*>(&sxs[0][0][0]);
        #pragma unroll
        for (int bs = 0; bs < 2; ++bs) {
            const float4* s4 = reinterpret_cast<const float4*>(
                xs + ((size_t)((bb * 2 + bs) * 8 + h)) * 8192);
            #pragma unroll
            for (int k = 0; k < 8; ++k)
                dst[bs * 2048 + k * 256 + tt] = s4[k * 256 + tt];
        }
    }
    __syncthreads();

    const int m    = tt & 63;
    const int osub = tt >> 6;            // 0..3
    const int o0   = og * 8 + osub * 2;  // 2 o per thread

    float re[2][2], im[2][2];            // [oo][bs]
    #pragma unroll
    for (int oo = 0; oo < 2; ++oo)
        #pragma unroll
        for (int bs = 0; bs < 2; ++bs) { re[oo][bs] = 0.f; im[oo][bs] = 0.f; }

    const float* w1p = w1 + (size_t)h * (NE * NE * NM) + (size_t)o0 * NM + m;
    const float* w2p = w2 + (size_t)h * (NE * NE * NM) + (size_t)o0 * NM + m;

    #pragma unroll 2
    for (int i = 0; i < NE; ++i) {
        float wr0 = w1p[(size_t)i * (NE * NM)];
        float wi0 = w2p[(size_t)i * (NE * NM)];
        float wr1 = w1p[(size_t)i * (NE * NM) + NM];
        float wi1 = w2p[(size_t)i * (NE * NM) + NM];
        #pragma unroll
        for (int bs = 0; bs < 2; ++bs) {
            float2 xv = sxs[bs][i][m];
            re[0][bs] = fmaf(xv.x, wr0, fmaf(-xv.y, wi0, re[0][bs]));
            im[0][bs] = fmaf(xv.x, wi0, fmaf( xv.y, wr0, im[0][bs]));
            re[1][bs] = fmaf(xv.x, wr1, fmaf(-xv.y, wi1, re[1][bs]));
            im[1][bs] = fmaf(xv.x, wi1, fmaf( xv.y, wr1, im[1][bs]));
        }
    }

    const float sca = (m == 0 ? 1.0f : 2.0f) / (float)LN;  // (2-delta_m0)/L fold
    const int kk  = m >> 4;
    const int khi = ((m & 15) >> 2) * 16;
    const int jj  = (m & 3) << 1;
    #pragma unroll
    for (int oo = 0; oo < 2; ++oo) {
        const int c = h * 64 + o0 + oo;
        #pragma unroll
        for (int bs = 0; bs < 2; ++bs) {
            const int b = bb * 2 + bs;
            size_t slot = (((size_t)b * 4 + kk) * 32 + (c >> 4)) * 64 + khi + (c & 15);
            unsigned int pk = (unsigned)bf16bits(re[oo][bs] * sca) |
                              ((unsigned)bf16bits(-im[oo][bs] * sca) << 16);
            *reinterpret_cast<unsigned int*>(gf + slot * 8 + jj) = pk;
        }
    }
}

// Stage 3 MFMA: per b: out[l][c] = sum_mp T[l][mp] * G[mp][c].  M=c(128/block), N=l(64/block), K=128.
// grid (64 lb, 4 cb, 8 b), block 256 = 4 waves; wave w owns c-quarter [w*32, w*32+32).
// Zero LDS / zero barriers; both operand tables stream from L2.
__global__ __launch_bounds__(256, 2) void k_s3(const unsigned short* __restrict__ gf,
                                               const unsigned short* __restrict__ tfp,
                                               float* __restrict__ out) {
    const int lb = blockIdx.x;   // l base = lb*64
    const int cb = blockIdx.y;   // c base = cb*128
    const int b  = blockIdx.z;
    const int tid = threadIdx.x;
    const int w = tid >> 6, lane = tid & 63;

    const unsigned short* ga = gf + ((((size_t)b * 4) * 32 + cb * 8 + w * 2) * 64 + lane) * 8;
    const unsigned short* tb = tfp + (((size_t)lb * 4) * 64 + lane) * 8;

    f32x4 acc[2][4] = {};
    s16x8 af[3][2], bf[3][4];

#define S3_LOAD(T, SLOT)                                                          \
    {                                                                             \
        const unsigned short* gp_ = ga + (size_t)(T) * (32 * 64 * 8);             \
        const unsigned short* tp_ = tb + (size_t)(T) * (256 * 64 * 8);            \
        af[SLOT][0] = *reinterpret_cast<const s16x8*>(gp_);                       \
        af[SLOT][1] = *reinterpret_cast<const s16x8*>(gp_ + 64 * 8);              \
        bf[SLOT][0] = *reinterpret_cast<const s16x8*>(tp_);                       \
        bf[SLOT][1] = *reinterpret_cast<const s16x8*>(tp_ + 64 * 8);              \
        bf[SLOT][2] = *reinterpret_cast<const s16x8*>(tp_ + 2 * 64 * 8);          \
        bf[SLOT][3] = *reinterpret_cast<const s16x8*>(tp_ + 3 * 64 * 8);          \
    }

    S3_LOAD(0, 0)
    S3_LOAD(1, 1)

    #pragma unroll
    for (int t = 0; t < 4; ++t) {
        const int slot = t % 3;
        if (t + 2 < 4) { const int ns = (t + 2) % 3; S3_LOAD(t + 2, ns) }
        #pragma unroll
        for (int mi = 0; mi < 2; ++mi)
            #pragma unroll
            for (int ni = 0; ni < 4; ++ni)
                acc[mi][ni] = __builtin_amdgcn_mfma_f32_16x16x32_bf16(
                    af[slot][mi], bf[slot][ni], acc[mi][ni], 0, 0, 0);
    }
#undef S3_LOAD

    // D[row=c_local][col=l_local]; f32x4 regs span 4 consecutive c.
    const int c0 = cb * 128 + w * 32 + (lane >> 4) * 4;
    const int l0 = lb * 64 + (lane & 15);
    #pragma unroll
    for (int mi = 0; mi < 2; ++mi)
        #pragma unroll
        for (int ni = 0; ni < 4; ++ni) {
            float* op = out + ((size_t)b * LN + l0 + ni * 16) * NC + c0 + mi * 16;
            *reinterpret_cast<f32x4*>(op) = acc[mi][ni];
        }
}

extern "C" void kernel_launch(void* const* d_in, const int* in_sizes, int n_in,
                              void* d_out, int out_size, void* d_ws, size_t ws_size,
                              hipStream_t stream) {
    const float* q  = (const float*)d_in[0];
    // d_in[1] (k) and d_in[2] (v) are unused by the reference
    const float* w1 = (const float*)d_in[3];
    const float* w2 = (const float*)d_in[4];
    float* out = (float*)d_out;
    float* ws  = (float*)d_ws;

    unsigned short* egf = (unsigned short*)(ws + WS_EGF);
    unsigned short* tfp = (unsigned short*)(ws + WS_TF);
    unsigned short* gf  = (unsigned short*)(ws + WS_GF);
    unsigned short* qtf = (unsigned short*)(ws + WS_QTF);
    float*          xp  = ws + WS_XP;
    float*          xs  = ws + WS_XS;

    k_pre<<<8704, 256, 0, stream>>>(q, qtf, egf, tfp);
    k_s1<<<dim3(8, NH, NB), 256, 0, stream>>>(qtf, egf, xp);
    k_presum<<<512, 256, 0, stream>>>(xp, xs);
    k_s2<<<256, 256, 0, stream>>>(w1, w2, xs, gf);
    k_s3<<<dim3(64, 4, NB), 256, 0, stream>>>(gf, tfp, out);
}